// Round 7
// baseline (226.295 us; speedup 1.0000x reference)
//
#include <hip/hip_runtime.h>
#include <stdint.h>

// ---------------------------------------------------------------------------
// KDGQA: x -> (Q,K,V) proj -> dynamic KV allocation from ||K||_F -> grouped
// attention -> output proj + bias.  B=8, P=1024, DIM=1024, H=16, KV=8, HD=64.
// R7: attn restructured to ONE barrier per K-tile with LDS double-buffering
// (R6 was exactly neutral despite -96cyc DS -> attn is barrier/latency-bound,
// not DS-throughput-bound). While computing tile kt from buf p, tile kt+1 is
// staged into buf 1-p (gll K + V regs loaded one iteration earlier); the
// end-of-tile barrier drains loads that had a full compute phase in flight.
// ---------------------------------------------------------------------------

typedef float f32x4 __attribute__((ext_vector_type(4)));
typedef short s16x8 __attribute__((ext_vector_type(8)));
typedef short s16x4 __attribute__((ext_vector_type(4)));
typedef int   i32x4 __attribute__((ext_vector_type(4)));

__device__ __forceinline__ unsigned short f2bf(float f) {
  unsigned int u = __builtin_bit_cast(unsigned int, f);
  u = (u + 0x7FFFu + ((u >> 16) & 1u)) >> 16;   // round-to-nearest-even
  return (unsigned short)u;
}

// packed fp32x2 -> bf16x2 (low = a, high = b)
__device__ __forceinline__ unsigned int pk_bf16(float a, float b) {
#if __has_builtin(__builtin_amdgcn_cvt_pk_bf16_f32)
  auto v = __builtin_amdgcn_cvt_pk_bf16_f32(a, b);
  return __builtin_bit_cast(unsigned int, v);
#else
  unsigned int ua = __builtin_bit_cast(unsigned int, a);
  unsigned int ub = __builtin_bit_cast(unsigned int, b);
  ua += 0x7FFFu + ((ua >> 16) & 1u);
  ub += 0x7FFFu + ((ub >> 16) & 1u);
#if __has_builtin(__builtin_amdgcn_perm)
  return __builtin_amdgcn_perm(ub, ua, 0x07060302);
#else
  return (ua >> 16) | (ub & 0xFFFF0000u);
#endif
#endif
}

// select lo16 (takeHi=0) or hi16 (takeHi=1) of two dwords into one dword
__device__ __forceinline__ unsigned int perm_half(unsigned int hi, unsigned int lo, int takeHi) {
#if __has_builtin(__builtin_amdgcn_perm)
  return __builtin_amdgcn_perm(hi, lo, takeHi ? 0x07060302u : 0x05040100u);
#else
  return takeHi ? ((lo >> 16) | (hi & 0xFFFF0000u)) : ((lo & 0xFFFFu) | (hi << 16));
#endif
}

__device__ __forceinline__ float fast_exp2(float x) {
#if __has_builtin(__builtin_amdgcn_exp2f)
  return __builtin_amdgcn_exp2f(x);
#else
  return exp2f(x);
#endif
}

#if __has_builtin(__builtin_amdgcn_global_load_lds)
#define HAVE_GLL 1
typedef const __attribute__((address_space(1))) void* gas_ptr;
typedef __attribute__((address_space(3))) void* las_ptr;
__device__ __forceinline__ void gll16(const void* g, void* l) {
  __builtin_amdgcn_global_load_lds((gas_ptr)g, (las_ptr)l, 16, 0, 0);
}
#endif

// ---------------------------------------------------------------------------
// 1. fp32 -> bf16 conversion. Wq gets 0.125 (HD^-0.5) * log2(e) folded in so
//    attention softmax is a raw exp2.  Block 0 also zeroes the sumsq cells.
// ---------------------------------------------------------------------------
__global__ void convert_kernel(const float* __restrict__ x, const float* __restrict__ Wq,
                               const float* __restrict__ Wk, const float* __restrict__ Wv,
                               const float* __restrict__ Wp,
                               unsigned short* __restrict__ xb,
                               unsigned short* __restrict__ wqkv,
                               unsigned short* __restrict__ wpb,
                               float* __restrict__ sums) {
  if (blockIdx.x == 0 && threadIdx.x < 64) sums[threadIdx.x] = 0.0f;
  const long i = ((long)blockIdx.x * 256 + threadIdx.x) * 4;
  const float* src; unsigned short* dst; long off; float scale = 1.0f;
  if (i < 8388608L)       { src = x;  dst = xb;             off = i;             }
  else if (i < 9437184L)  { src = Wq; dst = wqkv;           off = i - 8388608L;  scale = 0.18033688011112042f; }
  else if (i < 9961472L)  { src = Wk; dst = wqkv + 1048576; off = i - 9437184L;  }
  else if (i < 10485760L) { src = Wv; dst = wqkv + 1572864; off = i - 9961472L;  }
  else                    { src = Wp; dst = wpb;            off = i - 10485760L; }
  f32x4 v = *(const f32x4*)(src + off);
  s16x4 o;
  o[0] = (short)f2bf(v[0] * scale);
  o[1] = (short)f2bf(v[1] * scale);
  o[2] = (short)f2bf(v[2] * scale);
  o[3] = (short)f2bf(v[3] * scale);
  *(s16x4*)(dst + off) = o;
}

// ---------------------------------------------------------------------------
// 2. GEMM  C[M][N] = A[M][1024] * B[N][1024]^T, 128x128 tile, BK=64, m97-style
//    global_load_lds staging with XOR chunk swizzle.  DO_SUMSQ: K-range blocks
//    reduce sum(acc^2) per (b, kv head) into sums[] via one atomic per wave.
// ---------------------------------------------------------------------------
template<int N, bool OUT_BF16, bool DO_SUMSQ>
__global__ __launch_bounds__(256)
void gemm_bt(const unsigned short* __restrict__ A,
             const unsigned short* __restrict__ Bw,
             unsigned short* __restrict__ Cb,
             float* __restrict__ Cf,
             const float* __restrict__ bias,
             float* __restrict__ sums) {
  __shared__ __align__(16) unsigned short As[8192];   // 128 rows x 64 shorts
  __shared__ __align__(16) unsigned short Bs[8192];
  constexpr int NB = N / 128;
  const int bm = blockIdx.x / NB, bn = blockIdx.x % NB;
  const int m0 = bm * 128, n0 = bn * 128;
  const int t = threadIdx.x;
  const int w = t >> 6, lane = t & 63, quad = lane >> 4, ln = lane & 15;
  const int wm = w & 1, wn = w >> 1;

  const int lrow = lane >> 3;                       // 0..7
  const int lc8  = ((lane & 7) ^ lrow) << 3;        // logical chunk offset (shorts)
  const unsigned short* agl = A  + (m0 + w * 32 + lrow) * 1024 + lc8;
  const unsigned short* bgl = Bw + (n0 + w * 32 + lrow) * 1024 + lc8;

  f32x4 acc[4][4] = {};

  for (int k0 = 0; k0 < 1024; k0 += 64) {
    __syncthreads();
#ifdef HAVE_GLL
    #pragma unroll
    for (int c = 0; c < 4; ++c) {
      gll16(agl + k0 + c * 8192, &As[w * 2048 + c * 512]);
      gll16(bgl + k0 + c * 8192, &Bs[w * 2048 + c * 512]);
    }
#else
    i32x4 ra[4], rb[4];
    #pragma unroll
    for (int c = 0; c < 4; ++c) {
      ra[c] = *(const i32x4*)(agl + k0 + c * 8192);
      rb[c] = *(const i32x4*)(bgl + k0 + c * 8192);
    }
    #pragma unroll
    for (int c = 0; c < 4; ++c) {
      *(i32x4*)(&As[w * 2048 + c * 512 + lane * 8]) = ra[c];
      *(i32x4*)(&Bs[w * 2048 + c * 512 + lane * 8]) = rb[c];
    }
#endif
    __syncthreads();
    #pragma unroll
    for (int kc = 0; kc < 2; ++kc) {
      const int pcs = ((kc * 4 + quad) ^ (ln & 7)) << 3;
      s16x8 af[4], bf[4];
      #pragma unroll
      for (int i = 0; i < 4; ++i)
        af[i] = *(const s16x8*)(&As[(wm * 64 + i * 16 + ln) * 64 + pcs]);
      #pragma unroll
      for (int j = 0; j < 4; ++j)
        bf[j] = *(const s16x8*)(&Bs[(wn * 64 + j * 16 + ln) * 64 + pcs]);
      #pragma unroll
      for (int i = 0; i < 4; ++i)
        #pragma unroll
        for (int j = 0; j < 4; ++j)
          acc[i][j] = __builtin_amdgcn_mfma_f32_16x16x32_bf16(af[i], bf[j], acc[i][j], 0, 0, 0);
    }
  }

  if constexpr (DO_SUMSQ) {
    if (bn >= 8 && bn < 12) {
      float ss = 0.0f;
      #pragma unroll
      for (int i = 0; i < 4; ++i)
        #pragma unroll
        for (int j = 0; j < 4; ++j)
          #pragma unroll
          for (int r = 0; r < 4; ++r)
            ss += acc[i][j][r] * acc[i][j][r];
      #pragma unroll
      for (int off = 1; off < 64; off <<= 1) ss += __shfl_xor(ss, off);
      if (lane == 0)
        atomicAdd(&sums[(m0 >> 10) * 8 + (bn - 8) * 2 + wn], ss);
    }
  }

  // Epilogue. C/D layout: row = quad*4+reg, col = lane&15.
  #pragma unroll
  for (int j = 0; j < 4; ++j) {
    const int gn = n0 + wn * 64 + j * 16 + ln;
    float bv = 0.0f;
    if constexpr (!OUT_BF16) bv = bias[gn];
    #pragma unroll
    for (int i = 0; i < 4; ++i) {
      const int gm0 = m0 + wm * 64 + i * 16 + quad * 4;
      #pragma unroll
      for (int r = 0; r < 4; ++r) {
        float v = acc[i][j][r];
        if constexpr (OUT_BF16) Cb[(gm0 + r) * N + gn] = f2bf(v);
        else                    Cf[(gm0 + r) * N + gn] = v + bv;
      }
    }
  }
}

// ---------------------------------------------------------------------------
// 3. Attention. Block = 4 waves x 2 strips x 16 q = 128 queries of one (b,h).
//    Single barrier per K-tile + double-buffered K/V LDS: while computing
//    tile kt from buf p, tile kt+1 is staged into buf 1-p (K via gll with
//    XOR chunk swizzle; V from regs loaded during tile kt-1).  K fragments
//    hoisted once per tile; P = exp2(S) packed bf16 (pair-swizzled rows);
//    l accumulated by MFMA against a ones fragment.  LDS 52 KB -> 3 blk/CU.
// ---------------------------------------------------------------------------
__global__ __launch_bounds__(256, 3)
void attn_kernel(const unsigned short* __restrict__ qkv,
                 const float* __restrict__ sums,
                 unsigned short* __restrict__ att) {
  __shared__ __align__(16) unsigned short Ks[2][4096];   // 64 keys x 64 d, swizzled
  __shared__ __align__(16) unsigned short Vt[2][64][72]; // Vt[d][key]
  __shared__ __align__(16) unsigned int  Plb[4][32][36]; // per-wave packed P
  __shared__ int kvs;

  const int bid = blockIdx.x;
  const int h = bid & 15, qt = (bid >> 4) & 7, b = bid >> 7;
  const int t = threadIdx.x, w = t >> 6, lane = t & 63, quad = lane >> 4, ln = lane & 15;

  if (t == 0) {   // inline allocation (mirrors jax: round / first-argmax / searchsorted)
    float kn[8];
    for (int kv = 0; kv < 8; ++kv) {
      float s = 0.0f;
      for (int bb = 0; bb < 8; ++bb) s += sqrtf(sums[bb * 8 + kv]);
      kn[kv] = s;
    }
    float mn = kn[0], mx = kn[0];
    for (int i = 1; i < 8; ++i) { mn = fminf(mn, kn[i]); mx = fmaxf(mx, kn[i]); }
    float tot = 0.0f;
    for (int i = 0; i < 8; ++i) { kn[i] = (kn[i] - mn) / (mx - mn); tot += kn[i]; }
    int a[8], sum = 0;
    for (int i = 0; i < 8; ++i) { a[i] = (int)rintf(kn[i] * 16.0f / tot); sum += a[i]; }
    while (sum > 16) {
      int im = 0;
      for (int i = 1; i < 8; ++i) if (a[i] > a[im]) im = i;
      a[im]--; sum--;
    }
    while (sum < 16) {
      int im = 0;
      for (int i = 1; i < 8; ++i) if (a[i] < a[im]) im = i;
      a[im]++; sum++;
    }
    int cum = 0, idx = 0, c[8];
    for (int i = 0; i < 8; ++i) { cum += a[i]; c[i] = cum; }
    while (c[idx] <= h) idx++;
    kvs = idx;
  }
  __syncthreads();
  const int kvi = kvs;

  // Q fragments for both strips: A[m=ln][k=quad*8+j]
  s16x8 qf[2][2];
  #pragma unroll
  for (int s = 0; s < 2; ++s) {
    const unsigned short* qp = qkv + (b * 1024 + qt * 128 + s * 64 + w * 16 + ln) * 2048
                               + h * 64 + quad * 8;
    qf[s][0] = *(const s16x8*)(qp);
    qf[s][1] = *(const s16x8*)(qp + 32);
  }

  // K staging (gll, XOR swizzle): wave w stages keys w*16..w*16+15 (2 calls)
  const int lc8 = ((lane & 7) ^ (lane >> 3)) << 3;
  const unsigned short* kglA = qkv + (b * 1024 + w * 16 + (lane >> 3)) * 2048
                               + 1024 + kvi * 64 + lc8;
  const unsigned short* kglB = kglA + 8 * 2048;

  // V staging: thread covers keys (2kp,2kp+1) x d [vd0, vd0+8)
  const int kp = t & 31, vd0 = (t >> 5) << 3;
  const unsigned short* vbase = qkv + (b * 1024 + 2 * kp) * 2048 + 1536 + kvi * 64 + vd0;

  s16x8 ones;
  #pragma unroll
  for (int j = 0; j < 8; ++j) ones[j] = (short)0x3F80;   // bf16 1.0

  f32x4 Oa[2][4] = {};
  f32x4 lacc[2] = {};

  // ---- pipeline preamble: stage tile 0 into buf 0; load V(1) into regs ----
  s16x8 va0 = *(const s16x8*)(vbase);
  s16x8 va1 = *(const s16x8*)(vbase + 2048);
#ifdef HAVE_GLL
  gll16(kglA, &Ks[0][w * 1024]);
  gll16(kglB, &Ks[0][w * 1024 + 512]);
#else
  {
    i32x4 t0 = *(const i32x4*)(kglA);
    i32x4 t1 = *(const i32x4*)(kglB);
    *(i32x4*)(&Ks[0][w * 1024 + lane * 8]) = t0;
    *(i32x4*)(&Ks[0][w * 1024 + 512 + lane * 8]) = t1;
  }
#endif
  #pragma unroll
  for (int i = 0; i < 8; ++i) {
    unsigned int pk = (unsigned int)(unsigned short)va0[i] |
                      ((unsigned int)(unsigned short)va1[i] << 16);
    *(unsigned int*)(&Vt[0][vd0 + i][2 * kp]) = pk;
  }
  va0 = *(const s16x8*)(vbase + 131072);
  va1 = *(const s16x8*)(vbase + 131072 + 2048);
  __syncthreads();   // tile 0 ready (drains gll + Vt writes)

  for (int kt = 0; kt < 16; ++kt) {
    const int p = kt & 1, np = p ^ 1;

    // ---- stage tile kt+1 into buf np (overlapped with compute below) ----
    if (kt < 15) {
#ifdef HAVE_GLL
      gll16(kglA + (kt + 1) * 131072, &Ks[np][w * 1024]);
      gll16(kglB + (kt + 1) * 131072, &Ks[np][w * 1024 + 512]);
#else
      i32x4 t0 = *(const i32x4*)(kglA + (kt + 1) * 131072);
      i32x4 t1 = *(const i32x4*)(kglB + (kt + 1) * 131072);
      *(i32x4*)(&Ks[np][w * 1024 + lane * 8]) = t0;
      *(i32x4*)(&Ks[np][w * 1024 + 512 + lane * 8]) = t1;
#endif
      #pragma unroll
      for (int i = 0; i < 8; ++i) {   // va holds V(kt+1), loaded last iter
        unsigned int pk = (unsigned int)(unsigned short)va0[i] |
                          ((unsigned int)(unsigned short)va1[i] << 16);
        *(unsigned int*)(&Vt[np][vd0 + i][2 * kp]) = pk;
      }
      if (kt < 14) {   // issue V(kt+2) loads; full compute phase to land
        const unsigned short* q = vbase + (kt + 2) * 131072;
        va0 = *(const s16x8*)(q);
        va1 = *(const s16x8*)(q + 2048);
      }
    }

    // ---- compute tile kt from buf p ----
    // K fragments: read once, shared by both strips (8 b128 reads).
    s16x8 kfr[2][4];
    #pragma unroll
    for (int ks = 0; ks < 4; ++ks) {
      const int r0 = (ks * 16 + ln) * 64;
      kfr[0][ks] = *(const s16x8*)(&Ks[p][r0 + (((quad    ) ^ (ln & 7)) << 3)]);
      kfr[1][ks] = *(const s16x8*)(&Ks[p][r0 + (((quad + 4) ^ (ln & 7)) << 3)]);
    }

    // S per strip; exp2+pack into Plb rows (pair layout: col c<16 holds keys
    // (c, c+16); col 16+c holds keys (32+c, 48+c); 36-dword row pitch)
    #pragma unroll
    for (int s = 0; s < 2; ++s) {
      f32x4 sacc[4] = {};
      #pragma unroll
      for (int ks = 0; ks < 4; ++ks) {
        sacc[ks] = __builtin_amdgcn_mfma_f32_16x16x32_bf16(qf[s][0], kfr[0][ks], sacc[ks], 0, 0, 0);
        sacc[ks] = __builtin_amdgcn_mfma_f32_16x16x32_bf16(qf[s][1], kfr[1][ks], sacc[ks], 0, 0, 0);
      }
      #pragma unroll
      for (int r = 0; r < 4; ++r) {
        unsigned int d0 = pk_bf16(fast_exp2(sacc[0][r]), fast_exp2(sacc[1][r]));
        unsigned int d1 = pk_bf16(fast_exp2(sacc[2][r]), fast_exp2(sacc[3][r]));
        unsigned int* pr = &Plb[w][s * 16 + quad * 4 + r][0];
        pr[ln]      = d0;
        pr[ln + 16] = d1;
      }
    }
    __asm__ volatile("s_waitcnt lgkmcnt(0)" ::: "memory");  // Plb is wave-private

    // PV + l: A-frag from Plb (2x b128 + 4 perms per strip per kc)
    #pragma unroll
    for (int kc = 0; kc < 2; ++kc) {
      s16x8 pf[2];
      #pragma unroll
      for (int s = 0; s < 2; ++s) {
        const unsigned int* base = &Plb[w][s * 16 + ln][kc * 16 + (quad & 1) * 8];
        i32x4 u0 = *(const i32x4*)(base);
        i32x4 u1 = *(const i32x4*)(base + 4);
        const int th = quad >> 1;
        i32x4 pp;
        pp[0] = (int)perm_half((unsigned)u0[1], (unsigned)u0[0], th);
        pp[1] = (int)perm_half((unsigned)u0[3], (unsigned)u0[2], th);
        pp[2] = (int)perm_half((unsigned)u1[1], (unsigned)u1[0], th);
        pp[3] = (int)perm_half((unsigned)u1[3], (unsigned)u1[2], th);
        pf[s] = __builtin_bit_cast(s16x8, pp);
      }
      #pragma unroll
      for (int ds = 0; ds < 4; ++ds) {
        s16x8 vf = *(const s16x8*)(&Vt[p][ds * 16 + ln][kc * 32 + quad * 8]);
        Oa[0][ds] = __builtin_amdgcn_mfma_f32_16x16x32_bf16(pf[0], vf, Oa[0][ds], 0, 0, 0);
        Oa[1][ds] = __builtin_amdgcn_mfma_f32_16x16x32_bf16(pf[1], vf, Oa[1][ds], 0, 0, 0);
      }
      lacc[0] = __builtin_amdgcn_mfma_f32_16x16x32_bf16(pf[0], ones, lacc[0], 0, 0, 0);
      lacc[1] = __builtin_amdgcn_mfma_f32_16x16x32_bf16(pf[1], ones, lacc[1], 0, 0, 0);
    }

    // single barrier: staging of kt+1 complete AND buf p free for kt+2
    __syncthreads();
  }

  // finalize: O / l  (lacc rows = Oa rows; all cols of lacc identical)
  #pragma unroll
  for (int s = 0; s < 2; ++s) {
    float inv[4];
    #pragma unroll
    for (int r = 0; r < 4; ++r) inv[r] = 1.0f / lacc[s][r];
    const int orow = b * 1024 + qt * 128 + s * 64 + w * 16 + quad * 4;
    #pragma unroll
    for (int ds = 0; ds < 4; ++ds)
      #pragma unroll
      for (int r = 0; r < 4; ++r)
        att[(orow + r) * 1024 + h * 64 + ds * 16 + ln] = f2bf(Oa[s][ds][r] * inv[r]);
  }
}

// ---------------------------------------------------------------------------
// Workspace layout (bytes):
//   xb    @ 0          16,777,216   (bf16 8192x1024)  -- reused as att
//   wqkv  @ 16,777,216  4,194,304   (bf16 2048x1024: Wq*0.125*log2e | Wk | Wv)
//   wpb   @ 20,971,520  2,097,152   (bf16 1024x1024)
//   qkv   @ 23,068,672 33,554,432   (bf16 8192x2048)
//   sums  @ 56,623,104        256   (fp32 64: ||K||^2 per (b,kv))
// ---------------------------------------------------------------------------
extern "C" void kernel_launch(void* const* d_in, const int* in_sizes, int n_in,
                              void* d_out, int out_size, void* d_ws, size_t ws_size,
                              hipStream_t stream) {
  const float* x  = (const float*)d_in[0];
  const float* Wq = (const float*)d_in[1];
  const float* Wk = (const float*)d_in[2];
  const float* Wv = (const float*)d_in[3];
  const float* Wp = (const float*)d_in[4];
  const float* bp = (const float*)d_in[5];

  char* ws = (char*)d_ws;
  unsigned short* xb   = (unsigned short*)(ws);
  unsigned short* wqkv = (unsigned short*)(ws + 16777216);
  unsigned short* wpb  = (unsigned short*)(ws + 20971520);
  unsigned short* qkv  = (unsigned short*)(ws + 23068672);
  float*          sums = (float*)(ws + 56623104);
  unsigned short* att  = xb;   // xb dead after gemm1

  convert_kernel<<<11264, 256, 0, stream>>>(x, Wq, Wk, Wv, Wp, xb, wqkv, wpb, sums);
  gemm_bt<2048, true, true><<<1024, 256, 0, stream>>>(xb, wqkv, qkv, nullptr, nullptr, sums);
  attn_kernel<<<1024, 256, 0, stream>>>(qkv, sums, att);
  gemm_bt<1024, false, false><<<512, 256, 0, stream>>>(att, wpb, nullptr, (float*)d_out, bp, nullptr);
}

// Round 8
// 219.186 us; speedup vs baseline: 1.0324x; 1.0324x over previous
//
#include <hip/hip_runtime.h>
#include <stdint.h>

// ---------------------------------------------------------------------------
// KDGQA: x -> (Q,K,V) proj -> dynamic KV allocation from ||K||_F -> grouped
// attention -> output proj + bias.  B=8, P=1024, DIM=1024, H=16, KV=8, HD=64.
// R8: revert to R6 control flow (2-barrier, 4 blk/CU — R5/R7 proved occupancy
// is king).  NEW: S^T-with-permuted-keys transform.  S^T = K*Q^T (A=K, B=Q;
// same LDS reads) and keys within each 64-tile staged in order pi(m) =
// (m&0x20)|((m&0xC)<<1)|((m&0x10)>>2)|(m&3), so S^T's C-layout IS the PV
// B-fragment layout: P never touches LDS (no Plb, no perms, no mid-tile
// lgkm wait).  V stays natural (slot s == key s for both P and V).
// ---------------------------------------------------------------------------

typedef float f32x4 __attribute__((ext_vector_type(4)));
typedef int   i32x2 __attribute__((ext_vector_type(2)));
typedef short s16x8 __attribute__((ext_vector_type(8)));
typedef short s16x4 __attribute__((ext_vector_type(4)));
typedef int   i32x4 __attribute__((ext_vector_type(4)));

__device__ __forceinline__ unsigned short f2bf(float f) {
  unsigned int u = __builtin_bit_cast(unsigned int, f);
  u = (u + 0x7FFFu + ((u >> 16) & 1u)) >> 16;   // round-to-nearest-even
  return (unsigned short)u;
}

// packed fp32x2 -> bf16x2 (low = a, high = b)
__device__ __forceinline__ unsigned int pk_bf16(float a, float b) {
#if __has_builtin(__builtin_amdgcn_cvt_pk_bf16_f32)
  auto v = __builtin_amdgcn_cvt_pk_bf16_f32(a, b);
  return __builtin_bit_cast(unsigned int, v);
#else
  unsigned int ua = __builtin_bit_cast(unsigned int, a);
  unsigned int ub = __builtin_bit_cast(unsigned int, b);
  ua += 0x7FFFu + ((ua >> 16) & 1u);
  ub += 0x7FFFu + ((ub >> 16) & 1u);
#if __has_builtin(__builtin_amdgcn_perm)
  return __builtin_amdgcn_perm(ub, ua, 0x07060302);
#else
  return (ua >> 16) | (ub & 0xFFFF0000u);
#endif
#endif
}

__device__ __forceinline__ float fast_exp2(float x) {
#if __has_builtin(__builtin_amdgcn_exp2f)
  return __builtin_amdgcn_exp2f(x);
#else
  return exp2f(x);
#endif
}

#if __has_builtin(__builtin_amdgcn_global_load_lds)
#define HAVE_GLL 1
typedef const __attribute__((address_space(1))) void* gas_ptr;
typedef __attribute__((address_space(3))) void* las_ptr;
__device__ __forceinline__ void gll16(const void* g, void* l) {
  __builtin_amdgcn_global_load_lds((gas_ptr)g, (las_ptr)l, 16, 0, 0);
}
#endif

// ---------------------------------------------------------------------------
// 1. fp32 -> bf16 conversion. Wq gets 0.125 (HD^-0.5) * log2(e) folded in so
//    attention softmax is a raw exp2.  Block 0 also zeroes the sumsq cells.
// ---------------------------------------------------------------------------
__global__ void convert_kernel(const float* __restrict__ x, const float* __restrict__ Wq,
                               const float* __restrict__ Wk, const float* __restrict__ Wv,
                               const float* __restrict__ Wp,
                               unsigned short* __restrict__ xb,
                               unsigned short* __restrict__ wqkv,
                               unsigned short* __restrict__ wpb,
                               float* __restrict__ sums) {
  if (blockIdx.x == 0 && threadIdx.x < 64) sums[threadIdx.x] = 0.0f;
  const long i = ((long)blockIdx.x * 256 + threadIdx.x) * 4;
  const float* src; unsigned short* dst; long off; float scale = 1.0f;
  if (i < 8388608L)       { src = x;  dst = xb;             off = i;             }
  else if (i < 9437184L)  { src = Wq; dst = wqkv;           off = i - 8388608L;  scale = 0.18033688011112042f; }
  else if (i < 9961472L)  { src = Wk; dst = wqkv + 1048576; off = i - 9437184L;  }
  else if (i < 10485760L) { src = Wv; dst = wqkv + 1572864; off = i - 9961472L;  }
  else                    { src = Wp; dst = wpb;            off = i - 10485760L; }
  f32x4 v = *(const f32x4*)(src + off);
  s16x4 o;
  o[0] = (short)f2bf(v[0] * scale);
  o[1] = (short)f2bf(v[1] * scale);
  o[2] = (short)f2bf(v[2] * scale);
  o[3] = (short)f2bf(v[3] * scale);
  *(s16x4*)(dst + off) = o;
}

// ---------------------------------------------------------------------------
// 2. GEMM  C[M][N] = A[M][1024] * B[N][1024]^T, 128x128 tile, BK=64, m97-style
//    global_load_lds staging with XOR chunk swizzle.  DO_SUMSQ: K-range blocks
//    reduce sum(acc^2) per (b, kv head) into sums[] via one atomic per wave.
// ---------------------------------------------------------------------------
template<int N, bool OUT_BF16, bool DO_SUMSQ>
__global__ __launch_bounds__(256)
void gemm_bt(const unsigned short* __restrict__ A,
             const unsigned short* __restrict__ Bw,
             unsigned short* __restrict__ Cb,
             float* __restrict__ Cf,
             const float* __restrict__ bias,
             float* __restrict__ sums) {
  __shared__ __align__(16) unsigned short As[8192];   // 128 rows x 64 shorts
  __shared__ __align__(16) unsigned short Bs[8192];
  constexpr int NB = N / 128;
  const int bm = blockIdx.x / NB, bn = blockIdx.x % NB;
  const int m0 = bm * 128, n0 = bn * 128;
  const int t = threadIdx.x;
  const int w = t >> 6, lane = t & 63, quad = lane >> 4, ln = lane & 15;
  const int wm = w & 1, wn = w >> 1;

  const int lrow = lane >> 3;                       // 0..7
  const int lc8  = ((lane & 7) ^ lrow) << 3;        // logical chunk offset (shorts)
  const unsigned short* agl = A  + (m0 + w * 32 + lrow) * 1024 + lc8;
  const unsigned short* bgl = Bw + (n0 + w * 32 + lrow) * 1024 + lc8;

  f32x4 acc[4][4] = {};

  for (int k0 = 0; k0 < 1024; k0 += 64) {
    __syncthreads();
#ifdef HAVE_GLL
    #pragma unroll
    for (int c = 0; c < 4; ++c) {
      gll16(agl + k0 + c * 8192, &As[w * 2048 + c * 512]);
      gll16(bgl + k0 + c * 8192, &Bs[w * 2048 + c * 512]);
    }
#else
    i32x4 ra[4], rb[4];
    #pragma unroll
    for (int c = 0; c < 4; ++c) {
      ra[c] = *(const i32x4*)(agl + k0 + c * 8192);
      rb[c] = *(const i32x4*)(bgl + k0 + c * 8192);
    }
    #pragma unroll
    for (int c = 0; c < 4; ++c) {
      *(i32x4*)(&As[w * 2048 + c * 512 + lane * 8]) = ra[c];
      *(i32x4*)(&Bs[w * 2048 + c * 512 + lane * 8]) = rb[c];
    }
#endif
    __syncthreads();
    #pragma unroll
    for (int kc = 0; kc < 2; ++kc) {
      const int pcs = ((kc * 4 + quad) ^ (ln & 7)) << 3;
      s16x8 af[4], bf[4];
      #pragma unroll
      for (int i = 0; i < 4; ++i)
        af[i] = *(const s16x8*)(&As[(wm * 64 + i * 16 + ln) * 64 + pcs]);
      #pragma unroll
      for (int j = 0; j < 4; ++j)
        bf[j] = *(const s16x8*)(&Bs[(wn * 64 + j * 16 + ln) * 64 + pcs]);
      #pragma unroll
      for (int i = 0; i < 4; ++i)
        #pragma unroll
        for (int j = 0; j < 4; ++j)
          acc[i][j] = __builtin_amdgcn_mfma_f32_16x16x32_bf16(af[i], bf[j], acc[i][j], 0, 0, 0);
    }
  }

  if constexpr (DO_SUMSQ) {
    if (bn >= 8 && bn < 12) {
      float ss = 0.0f;
      #pragma unroll
      for (int i = 0; i < 4; ++i)
        #pragma unroll
        for (int j = 0; j < 4; ++j)
          #pragma unroll
          for (int r = 0; r < 4; ++r)
            ss += acc[i][j][r] * acc[i][j][r];
      #pragma unroll
      for (int off = 1; off < 64; off <<= 1) ss += __shfl_xor(ss, off);
      if (lane == 0)
        atomicAdd(&sums[(m0 >> 10) * 8 + (bn - 8) * 2 + wn], ss);
    }
  }

  // Epilogue. C/D layout: row = quad*4+reg, col = lane&15.
  #pragma unroll
  for (int j = 0; j < 4; ++j) {
    const int gn = n0 + wn * 64 + j * 16 + ln;
    float bv = 0.0f;
    if constexpr (!OUT_BF16) bv = bias[gn];
    #pragma unroll
    for (int i = 0; i < 4; ++i) {
      const int gm0 = m0 + wm * 64 + i * 16 + quad * 4;
      #pragma unroll
      for (int r = 0; r < 4; ++r) {
        float v = acc[i][j][r];
        if constexpr (OUT_BF16) Cb[(gm0 + r) * N + gn] = f2bf(v);
        else                    Cf[(gm0 + r) * N + gn] = v + bv;
      }
    }
  }
}

// ---------------------------------------------------------------------------
// 3. Attention. Block = 4 waves x 2 strips x 16 q = 128 queries of one (b,h).
//    R6 control flow (2 barriers/tile, single buffer, 4 blk/CU).  S^T form:
//    sacc = mfma(K_frag, Q_frag) -> C-layout [key][q]; keys staged permuted
//    (Ks row m <- global key pi(m)) so exp2(sacc) packs DIRECTLY into the PV
//    B-fragment.  PV: O^T = mfma(V^T_frag, P_frag); l = mfma(ones, P_frag).
//    LDS = Ks 8KB + Vt 9KB only.
// ---------------------------------------------------------------------------
__global__ __launch_bounds__(256, 4)
void attn_kernel(const unsigned short* __restrict__ qkv,
                 const float* __restrict__ sums,
                 unsigned short* __restrict__ att) {
  __shared__ __align__(16) unsigned short Ks[4096];      // 64 keys x 64 d, swizzled+permuted
  __shared__ __align__(16) unsigned short Vt[64][72];    // Vt[d][key], natural order
  __shared__ int kvs;

  const int bid = blockIdx.x;
  const int h = bid & 15, qt = (bid >> 4) & 7, b = bid >> 7;
  const int t = threadIdx.x, w = t >> 6, lane = t & 63, quad = lane >> 4, ln = lane & 15;

  if (t == 0) {   // inline allocation (mirrors jax: round / first-argmax / searchsorted)
    float kn[8];
    for (int kv = 0; kv < 8; ++kv) {
      float s = 0.0f;
      for (int bb = 0; bb < 8; ++bb) s += sqrtf(sums[bb * 8 + kv]);
      kn[kv] = s;
    }
    float mn = kn[0], mx = kn[0];
    for (int i = 1; i < 8; ++i) { mn = fminf(mn, kn[i]); mx = fmaxf(mx, kn[i]); }
    float tot = 0.0f;
    for (int i = 0; i < 8; ++i) { kn[i] = (kn[i] - mn) / (mx - mn); tot += kn[i]; }
    int a[8], sum = 0;
    for (int i = 0; i < 8; ++i) { a[i] = (int)rintf(kn[i] * 16.0f / tot); sum += a[i]; }
    while (sum > 16) {
      int im = 0;
      for (int i = 1; i < 8; ++i) if (a[i] > a[im]) im = i;
      a[im]--; sum--;
    }
    while (sum < 16) {
      int im = 0;
      for (int i = 1; i < 8; ++i) if (a[i] < a[im]) im = i;
      a[im]++; sum++;
    }
    int cum = 0, idx = 0, c[8];
    for (int i = 0; i < 8; ++i) { cum += a[i]; c[i] = cum; }
    while (c[idx] <= h) idx++;
    kvs = idx;
  }
  __syncthreads();
  const int kvi = kvs;

  // Q fragments for both strips (B-operand of S^T): Q[q=ln][d=quad*8+j]
  s16x8 qf[2][2];
  #pragma unroll
  for (int s = 0; s < 2; ++s) {
    const unsigned short* qp = qkv + (b * 1024 + qt * 128 + s * 64 + w * 16 + ln) * 2048
                               + h * 64 + quad * 8;
    qf[s][0] = *(const s16x8*)(qp);
    qf[s][1] = *(const s16x8*)(qp + 32);
  }

  // K staging (gll, XOR chunk swizzle + key permutation pi):
  // Ks row m holds global key kt*64 + pi(m),  pi(m) = m5 | q1 q0 | ks0 | r1 r0.
  const int lc8 = ((lane & 7) ^ (lane >> 3)) << 3;
  const int mA = w * 16 + (lane >> 3);          // LDS rows staged by call A
  const int mB = mA + 8;                        // call B
  const int gA = (mA & 0x20) | ((mA & 0x0C) << 1) | ((mA & 0x10) >> 2) | (mA & 3);
  const int gB = (mB & 0x20) | ((mB & 0x0C) << 1) | ((mB & 0x10) >> 2) | (mB & 3);
  const unsigned short* kglA = qkv + (b * 1024 + gA) * 2048 + 1024 + kvi * 64 + lc8;
  const unsigned short* kglB = qkv + (b * 1024 + gB) * 2048 + 1024 + kvi * 64 + lc8;

  // V staging (natural key order): thread covers keys (2kp,2kp+1) x d [vd0,+8)
  const int kp = t & 31, vd0 = (t >> 5) << 3;
  const unsigned short* vbase = qkv + (b * 1024 + 2 * kp) * 2048 + 1536 + kvi * 64 + vd0;

  s16x8 ones;
  #pragma unroll
  for (int j = 0; j < 8; ++j) ones[j] = (short)0x3F80;   // bf16 1.0

  f32x4 Oa[2][4] = {};    // O^T frags: lane holds O^T[d=ds*16+quad*4+r][q=ln]
  f32x4 lacc[2] = {};

  s16x8 va0 = *(const s16x8*)(vbase);
  s16x8 va1 = *(const s16x8*)(vbase + 2048);

  for (int kt = 0; kt < 16; ++kt) {
    __syncthreads();
#ifdef HAVE_GLL
    gll16(kglA + kt * 131072, Ks + w * 1024);
    gll16(kglB + kt * 131072, Ks + w * 1024 + 512);
#else
    i32x4 t0 = *(const i32x4*)(kglA + kt * 131072);
    i32x4 t1 = *(const i32x4*)(kglB + kt * 131072);
    *(i32x4*)(Ks + w * 1024 + lane * 8) = t0;
    *(i32x4*)(Ks + w * 1024 + 512 + lane * 8) = t1;
#endif
    #pragma unroll
    for (int i = 0; i < 8; ++i) {
      unsigned int pk = (unsigned int)(unsigned short)va0[i] |
                        ((unsigned int)(unsigned short)va1[i] << 16);
      *(unsigned int*)(&Vt[vd0 + i][2 * kp]) = pk;
    }
    __syncthreads();

    if (kt < 15) {   // prefetch next V tile (drains at NEXT tile's barrier)
      const unsigned short* q = vbase + (kt + 1) * 131072;
      va0 = *(const s16x8*)(q);
      va1 = *(const s16x8*)(q + 2048);
    }

    // K fragments (A-operand of S^T): read once, shared by both strips.
    s16x8 kfr[2][4];
    #pragma unroll
    for (int ks = 0; ks < 4; ++ks) {
      const int r0 = (ks * 16 + ln) * 64;
      kfr[0][ks] = *(const s16x8*)(Ks + r0 + (((quad    ) ^ (ln & 7)) << 3));
      kfr[1][ks] = *(const s16x8*)(Ks + r0 + (((quad + 4) ^ (ln & 7)) << 3));
    }

    // S^T per strip, then pack P directly into PV B-fragments (no LDS!).
    // sacc[ks][r] = S^T[slot 32*(ks>>1)+8*quad+4*(ks&1)+r][q=ln]  (via pi)
    // pf[kc] element j = P[slot kc*32+quad*8+j][q=ln]
    s16x8 pfs[2][2];
    #pragma unroll
    for (int s = 0; s < 2; ++s) {
      f32x4 sacc[4] = {};
      #pragma unroll
      for (int ks = 0; ks < 4; ++ks) {
        sacc[ks] = __builtin_amdgcn_mfma_f32_16x16x32_bf16(kfr[0][ks], qf[s][0], sacc[ks], 0, 0, 0);
        sacc[ks] = __builtin_amdgcn_mfma_f32_16x16x32_bf16(kfr[1][ks], qf[s][1], sacc[ks], 0, 0, 0);
      }
      #pragma unroll
      for (int kc = 0; kc < 2; ++kc) {
        i32x4 pd;
        pd[0] = (int)pk_bf16(fast_exp2(sacc[2*kc][0]),   fast_exp2(sacc[2*kc][1]));
        pd[1] = (int)pk_bf16(fast_exp2(sacc[2*kc][2]),   fast_exp2(sacc[2*kc][3]));
        pd[2] = (int)pk_bf16(fast_exp2(sacc[2*kc+1][0]), fast_exp2(sacc[2*kc+1][1]));
        pd[3] = (int)pk_bf16(fast_exp2(sacc[2*kc+1][2]), fast_exp2(sacc[2*kc+1][3]));
        pfs[s][kc] = __builtin_bit_cast(s16x8, pd);
      }
    }

    // PV + l:  O^T[d][q] += V^T[d][slot] * P[slot][q];  A = V^T frag from Vt.
    #pragma unroll
    for (int kc = 0; kc < 2; ++kc) {
      #pragma unroll
      for (int ds = 0; ds < 4; ++ds) {
        s16x8 vf = *(const s16x8*)(&Vt[ds * 16 + ln][kc * 32 + quad * 8]);
        Oa[0][ds] = __builtin_amdgcn_mfma_f32_16x16x32_bf16(vf, pfs[0][kc], Oa[0][ds], 0, 0, 0);
        Oa[1][ds] = __builtin_amdgcn_mfma_f32_16x16x32_bf16(vf, pfs[1][kc], Oa[1][ds], 0, 0, 0);
      }
      lacc[0] = __builtin_amdgcn_mfma_f32_16x16x32_bf16(ones, pfs[0][kc], lacc[0], 0, 0, 0);
      lacc[1] = __builtin_amdgcn_mfma_f32_16x16x32_bf16(ones, pfs[1][kc], lacc[1], 0, 0, 0);
    }
  }

  // finalize: O^T / l.  lacc rows all equal l[q=ln] -> ONE rcp per lane/strip.
  // Store: lane holds 4 consecutive d per ds -> one 8B store each.
  #pragma unroll
  for (int s = 0; s < 2; ++s) {
    const float inv = 1.0f / lacc[s][0];
    unsigned short* orow = att + (b * 1024 + qt * 128 + s * 64 + w * 16 + ln) * 1024
                           + h * 64 + quad * 4;
    #pragma unroll
    for (int ds = 0; ds < 4; ++ds) {
      i32x2 pk;
      pk[0] = (int)pk_bf16(Oa[s][ds][0] * inv, Oa[s][ds][1] * inv);
      pk[1] = (int)pk_bf16(Oa[s][ds][2] * inv, Oa[s][ds][3] * inv);
      *(i32x2*)(orow + ds * 16) = pk;
    }
  }
}

// ---------------------------------------------------------------------------
// Workspace layout (bytes):
//   xb    @ 0          16,777,216   (bf16 8192x1024)  -- reused as att
//   wqkv  @ 16,777,216  4,194,304   (bf16 2048x1024: Wq*0.125*log2e | Wk | Wv)
//   wpb   @ 20,971,520  2,097,152   (bf16 1024x1024)
//   qkv   @ 23,068,672 33,554,432   (bf16 8192x2048)
//   sums  @ 56,623,104        256   (fp32 64: ||K||^2 per (b,kv))
// ---------------------------------------------------------------------------
extern "C" void kernel_launch(void* const* d_in, const int* in_sizes, int n_in,
                              void* d_out, int out_size, void* d_ws, size_t ws_size,
                              hipStream_t stream) {
  const float* x  = (const float*)d_in[0];
  const float* Wq = (const float*)d_in[1];
  const float* Wk = (const float*)d_in[2];
  const float* Wv = (const float*)d_in[3];
  const float* Wp = (const float*)d_in[4];
  const float* bp = (const float*)d_in[5];

  char* ws = (char*)d_ws;
  unsigned short* xb   = (unsigned short*)(ws);
  unsigned short* wqkv = (unsigned short*)(ws + 16777216);
  unsigned short* wpb  = (unsigned short*)(ws + 20971520);
  unsigned short* qkv  = (unsigned short*)(ws + 23068672);
  float*          sums = (float*)(ws + 56623104);
  unsigned short* att  = xb;   // xb dead after gemm1

  convert_kernel<<<11264, 256, 0, stream>>>(x, Wq, Wk, Wv, Wp, xb, wqkv, wpb, sums);
  gemm_bt<2048, true, true><<<1024, 256, 0, stream>>>(xb, wqkv, qkv, nullptr, nullptr, sums);
  attn_kernel<<<1024, 256, 0, stream>>>(qkv, sums, att);
  gemm_bt<1024, false, false><<<512, 256, 0, stream>>>(att, wpb, nullptr, (float*)d_out, bp, nullptr);
}